// Round 1
// baseline (427.209 us; speedup 1.0000x reference)
//
#include <hip/hip_runtime.h>
#include <hip/hip_bf16.h>

#define T_TOK 4096
#define DDIM  768
#define IDIM  2048
#define NEXP  8
#define LSTR  40   // LDS row stride in bf16 elems (80 B): 20 banks, ~2-way, 16B-aligned

typedef __attribute__((ext_vector_type(8))) short  bfrag;   // 8 bf16 = 4 VGPR
typedef __attribute__((ext_vector_type(4))) float  ffrag;   // 4 f32 acc

static __device__ __forceinline__ unsigned short f2bf(float f) {
    union { float f; unsigned u; } v; v.f = f;
    unsigned r = v.u + 0x7FFFu + ((v.u >> 16) & 1u);   // RNE
    return (unsigned short)(r >> 16);
}

static __device__ __forceinline__ unsigned cvt2(float x, float y) {
    return (unsigned)f2bf(x) | ((unsigned)f2bf(y) << 16);
}

// Barrier that does NOT drain vmcnt: prefetched global loads stay in flight.
// (lgkmcnt(0) seals our ds_writes/ds_reads; other waves' arrival implies theirs.)
#define PIPE_BAR() do { \
    asm volatile("s_waitcnt lgkmcnt(0)" ::: "memory"); \
    __builtin_amdgcn_s_barrier(); \
    __builtin_amdgcn_sched_barrier(0); \
} while (0)

// ws int layout: counts[8] @0, offsets[9] @16
__global__ void k_sort(const int* __restrict__ pos, int* __restrict__ ws_i,
                       int* __restrict__ perm) {
    __shared__ int hist[NEXP], cursor[NEXP];
    const int tid = threadIdx.x;
    if (tid < NEXP) hist[tid] = 0;
    __syncthreads();
    for (int i = tid; i < T_TOK; i += 1024)
        atomicAdd(&hist[pos[i]], 1);
    __syncthreads();
    if (tid == 0) {
        int s = 0;
        for (int e = 0; e < NEXP; ++e) {
            cursor[e] = s;
            ws_i[e] = hist[e];
            ws_i[16 + e] = s;
            s += hist[e];
        }
        ws_i[16 + NEXP] = s;
    }
    __syncthreads();
    for (int i = tid; i < T_TOK; i += 1024) {
        int p = atomicAdd(&cursor[pos[i]], 1);
        perm[p] = i;
    }
}

__global__ void k_gather(const float* __restrict__ x, const int* __restrict__ perm,
                         unsigned short* __restrict__ xg) {
    int p = blockIdx.x;
    int tok = perm[p];
    int j = threadIdx.x * 4;
    const float4 v = *reinterpret_cast<const float4*>(x + (size_t)tok * DDIM + j);
    uint2 o;
    o.x = cvt2(v.x, v.y);
    o.y = cvt2(v.z, v.w);
    *reinterpret_cast<uint2*>(xg + (size_t)p * DDIM + j) = o;
}

// GEMM1: xg[cnt x 768] bf16 @ gate/up^T -> h = silu(g)*u, bf16
// BM=128, BN=64 (each matrix), BK=32; LDS double-buffer + 2-deep reg prefetch,
// cross-barrier in-flight loads (raw s_barrier, no vmcnt drain).
__launch_bounds__(256, 3)
__global__ void k_gemm1(const unsigned short* __restrict__ xg,
                        const float* __restrict__ gate_w,
                        const float* __restrict__ up_w,
                        unsigned short* __restrict__ hg,
                        const int* __restrict__ ws_i) {
    const int e   = blockIdx.z;
    const int cnt = ws_i[e];
    const int m0  = blockIdx.y * 128;
    if (m0 >= cnt) return;
    const int off = ws_i[16 + e];
    const int n0  = blockIdx.x * 64;

    const int tid  = threadIdx.x;
    const int lane = tid & 63;
    const int wave = tid >> 6;
    const int wm   = wave & 1;
    const int wn   = wave >> 1;

    __shared__ __align__(16) unsigned short lsA[2][128 * LSTR];
    __shared__ __align__(16) unsigned short lsG[2][64 * LSTR];
    __shared__ __align__(16) unsigned short lsU[2][64 * LSTR];

    const float* gate_e = gate_w + (size_t)e * (IDIM * DDIM);
    const float* up_e   = up_w   + (size_t)e * (IDIM * DDIM);

    const int ar = tid >> 2;      // A rows 0..63 (+64)
    const int aq = tid & 3;
    const int br = tid >> 3;      // B rows 0..31 (+32)
    const int bq = tid & 7;

    int g0 = off + m0 + ar;      if (g0 > T_TOK - 1) g0 = T_TOK - 1;
    int g1 = off + m0 + ar + 64; if (g1 > T_TOK - 1) g1 = T_TOK - 1;
    const unsigned short* a0p = xg + (size_t)g0 * DDIM + aq * 8;
    const unsigned short* a1p = xg + (size_t)g1 * DDIM + aq * 8;
    const float* gp0 = gate_e + (size_t)(n0 + br)      * DDIM + bq * 4;
    const float* gp1 = gate_e + (size_t)(n0 + br + 32) * DDIM + bq * 4;
    const float* up0 = up_e   + (size_t)(n0 + br)      * DDIM + bq * 4;
    const float* up1 = up_e   + (size_t)(n0 + br + 32) * DDIM + bq * 4;

    ffrag accG[4][2], accU[4][2];
    const ffrag fz = {0.f, 0.f, 0.f, 0.f};
    for (int mi = 0; mi < 4; ++mi)
        for (int ni = 0; ni < 2; ++ni) { accG[mi][ni] = fz; accU[mi][ni] = fz; }

    const int koff = (lane >> 4) * 8;
    const int rsel = lane & 15;

    // two named prefetch register sets: E holds even tiles, O holds odd tiles
    uint4 Ea0, Ea1; float4 Eg0, Eg1, Eu0, Eu1;
    uint4 Oa0, Oa1; float4 Og0, Og1, Ou0, Ou1;

#define G1_LOAD(Pa0,Pa1,Pg0,Pg1,Pu0,Pu1, kb) do { \
    Pa0 = *reinterpret_cast<const uint4*>(a0p + (kb)); \
    Pa1 = *reinterpret_cast<const uint4*>(a1p + (kb)); \
    Pg0 = *reinterpret_cast<const float4*>(gp0 + (kb)); \
    Pg1 = *reinterpret_cast<const float4*>(gp1 + (kb)); \
    Pu0 = *reinterpret_cast<const float4*>(up0 + (kb)); \
    Pu1 = *reinterpret_cast<const float4*>(up1 + (kb)); } while (0)

#define G1_STORE(B, Pa0,Pa1,Pg0,Pg1,Pu0,Pu1) do { \
    *reinterpret_cast<uint4*>(&lsA[B][ar * LSTR + aq * 8])        = Pa0; \
    *reinterpret_cast<uint4*>(&lsA[B][(ar + 64) * LSTR + aq * 8]) = Pa1; \
    { uint2 o; o.x = cvt2(Pg0.x, Pg0.y); o.y = cvt2(Pg0.z, Pg0.w); \
      *reinterpret_cast<uint2*>(&lsG[B][br * LSTR + bq * 4]) = o; } \
    { uint2 o; o.x = cvt2(Pg1.x, Pg1.y); o.y = cvt2(Pg1.z, Pg1.w); \
      *reinterpret_cast<uint2*>(&lsG[B][(br + 32) * LSTR + bq * 4]) = o; } \
    { uint2 o; o.x = cvt2(Pu0.x, Pu0.y); o.y = cvt2(Pu0.z, Pu0.w); \
      *reinterpret_cast<uint2*>(&lsU[B][br * LSTR + bq * 4]) = o; } \
    { uint2 o; o.x = cvt2(Pu1.x, Pu1.y); o.y = cvt2(Pu1.z, Pu1.w); \
      *reinterpret_cast<uint2*>(&lsU[B][(br + 32) * LSTR + bq * 4]) = o; } } while (0)

#define G1_COMPUTE(B) do { \
    bfrag a[4], bg[2], bu[2]; \
    _Pragma("unroll") \
    for (int mi = 0; mi < 4; ++mi) \
        a[mi] = *reinterpret_cast<const bfrag*>(&lsA[B][(wm * 64 + mi * 16 + rsel) * LSTR + koff]); \
    _Pragma("unroll") \
    for (int ni = 0; ni < 2; ++ni) { \
        bg[ni] = *reinterpret_cast<const bfrag*>(&lsG[B][(wn * 32 + ni * 16 + rsel) * LSTR + koff]); \
        bu[ni] = *reinterpret_cast<const bfrag*>(&lsU[B][(wn * 32 + ni * 16 + rsel) * LSTR + koff]); \
    } \
    _Pragma("unroll") \
    for (int mi = 0; mi < 4; ++mi) { \
        _Pragma("unroll") \
        for (int ni = 0; ni < 2; ++ni) { \
            accG[mi][ni] = __builtin_amdgcn_mfma_f32_16x16x32_bf16(a[mi], bg[ni], accG[mi][ni], 0, 0, 0); \
            accU[mi][ni] = __builtin_amdgcn_mfma_f32_16x16x32_bf16(a[mi], bu[ni], accU[mi][ni], 0, 0, 0); \
        } \
    } } while (0)

    // prologue: tile0 -> E -> lds[0]; tile1 -> O (in flight across barrier)
    G1_LOAD(Ea0, Ea1, Eg0, Eg1, Eu0, Eu1, 0);
    G1_STORE(0, Ea0, Ea1, Eg0, Eg1, Eu0, Eu1);
    G1_LOAD(Oa0, Oa1, Og0, Og1, Ou0, Ou1, 32);
    PIPE_BAR();

    for (int kt = 0; kt < 24; kt += 2) {
        // even phase: compute tile kt from lds[0]; load kt+2 -> E; write O(kt+1) -> lds[1]
        if (kt + 2 < 24) G1_LOAD(Ea0, Ea1, Eg0, Eg1, Eu0, Eu1, kt * 32 + 64);
        G1_COMPUTE(0);
        G1_STORE(1, Oa0, Oa1, Og0, Og1, Ou0, Ou1);
        PIPE_BAR();
        // odd phase: compute tile kt+1 from lds[1]; load kt+3 -> O; write E(kt+2) -> lds[0]
        if (kt + 3 < 24) G1_LOAD(Oa0, Oa1, Og0, Og1, Ou0, Ou1, kt * 32 + 96);
        G1_COMPUTE(1);
        if (kt + 2 < 24) G1_STORE(0, Ea0, Ea1, Eg0, Eg1, Eu0, Eu1);
        PIPE_BAR();
    }
#undef G1_LOAD
#undef G1_STORE
#undef G1_COMPUTE

    // epilogue: h = silu(g)*u; C layout col=lane&15, row=(lane>>4)*4+r
    const int colb  = lane & 15;
    const int rquad = (lane >> 4) * 4;
    #pragma unroll
    for (int mi = 0; mi < 4; ++mi)
        #pragma unroll
        for (int ni = 0; ni < 2; ++ni) {
            int n = n0 + wn * 32 + ni * 16 + colb;
            #pragma unroll
            for (int r = 0; r < 4; ++r) {
                int ml = wm * 64 + mi * 16 + rquad + r;
                if (m0 + ml < cnt) {
                    float g = accG[mi][ni][r];
                    float u = accU[mi][ni][r];
                    float h = (g / (1.0f + __expf(-g))) * u;
                    hg[(size_t)(off + m0 + ml) * IDIM + n] = f2bf(h);
                }
            }
        }
}

// GEMM2: hg[cnt x 2048] bf16 @ down^T, full K (no split-K, no atomics),
// BM=64, BN=64, BK=32; same double-buffer pipeline; direct permuted store.
__launch_bounds__(256, 4)
__global__ void k_gemm2(const unsigned short* __restrict__ hg,
                        const float* __restrict__ down_w,
                        float* __restrict__ out,
                        const int* __restrict__ ws_i,
                        const int* __restrict__ perm) {
    const int e   = blockIdx.z;
    const int cnt = ws_i[e];
    const int m0  = blockIdx.y * 64;
    if (m0 >= cnt) return;
    const int off = ws_i[16 + e];
    const int n0  = blockIdx.x * 64;

    const int tid  = threadIdx.x;
    const int lane = tid & 63;
    const int wave = tid >> 6;
    const int wm   = wave & 1;
    const int wn   = wave >> 1;

    __shared__ __align__(16) unsigned short lsA[2][64 * LSTR];
    __shared__ __align__(16) unsigned short lsB[2][64 * LSTR];

    const float* down_e = down_w + (size_t)e * (DDIM * IDIM);

    const int ar = tid >> 2;      // A rows 0..63
    const int aq = tid & 3;
    const int br = tid >> 3;      // B rows 0..31 (+32)
    const int bq = tid & 7;

    int g0 = off + m0 + ar; if (g0 > T_TOK - 1) g0 = T_TOK - 1;
    const unsigned short* a0p = hg + (size_t)g0 * IDIM + aq * 8;
    const float* bp0 = down_e + (size_t)(n0 + br)      * IDIM + bq * 4;
    const float* bp1 = down_e + (size_t)(n0 + br + 32) * IDIM + bq * 4;

    ffrag acc[2][2];
    const ffrag fz = {0.f, 0.f, 0.f, 0.f};
    for (int mi = 0; mi < 2; ++mi)
        for (int ni = 0; ni < 2; ++ni) acc[mi][ni] = fz;

    const int koff = (lane >> 4) * 8;
    const int rsel = lane & 15;

    uint4 Ea; float4 Eb0, Eb1;
    uint4 Oa; float4 Ob0, Ob1;

#define G2_LOAD(Pa,Pb0,Pb1, kb) do { \
    Pa  = *reinterpret_cast<const uint4*>(a0p + (kb)); \
    Pb0 = *reinterpret_cast<const float4*>(bp0 + (kb)); \
    Pb1 = *reinterpret_cast<const float4*>(bp1 + (kb)); } while (0)

#define G2_STORE(B, Pa,Pb0,Pb1) do { \
    *reinterpret_cast<uint4*>(&lsA[B][ar * LSTR + aq * 8]) = Pa; \
    { uint2 o; o.x = cvt2(Pb0.x, Pb0.y); o.y = cvt2(Pb0.z, Pb0.w); \
      *reinterpret_cast<uint2*>(&lsB[B][br * LSTR + bq * 4]) = o; } \
    { uint2 o; o.x = cvt2(Pb1.x, Pb1.y); o.y = cvt2(Pb1.z, Pb1.w); \
      *reinterpret_cast<uint2*>(&lsB[B][(br + 32) * LSTR + bq * 4]) = o; } } while (0)

#define G2_COMPUTE(B) do { \
    bfrag a[2], b[2]; \
    _Pragma("unroll") \
    for (int mi = 0; mi < 2; ++mi) \
        a[mi] = *reinterpret_cast<const bfrag*>(&lsA[B][(wm * 32 + mi * 16 + rsel) * LSTR + koff]); \
    _Pragma("unroll") \
    for (int ni = 0; ni < 2; ++ni) \
        b[ni] = *reinterpret_cast<const bfrag*>(&lsB[B][(wn * 32 + ni * 16 + rsel) * LSTR + koff]); \
    _Pragma("unroll") \
    for (int mi = 0; mi < 2; ++mi) { \
        _Pragma("unroll") \
        for (int ni = 0; ni < 2; ++ni) \
            acc[mi][ni] = __builtin_amdgcn_mfma_f32_16x16x32_bf16(a[mi], b[ni], acc[mi][ni], 0, 0, 0); \
    } } while (0)

    G2_LOAD(Ea, Eb0, Eb1, 0);
    G2_STORE(0, Ea, Eb0, Eb1);
    G2_LOAD(Oa, Ob0, Ob1, 32);
    PIPE_BAR();

    for (int kt = 0; kt < 64; kt += 2) {
        if (kt + 2 < 64) G2_LOAD(Ea, Eb0, Eb1, kt * 32 + 64);
        G2_COMPUTE(0);
        G2_STORE(1, Oa, Ob0, Ob1);
        PIPE_BAR();
        if (kt + 3 < 64) G2_LOAD(Oa, Ob0, Ob1, kt * 32 + 96);
        G2_COMPUTE(1);
        if (kt + 2 < 64) G2_STORE(0, Ea, Eb0, Eb1);
        PIPE_BAR();
    }
#undef G2_LOAD
#undef G2_STORE
#undef G2_COMPUTE

    // epilogue: direct permuted store (each (tok, n) written exactly once)
    const int colb  = lane & 15;
    const int rquad = (lane >> 4) * 4;
    #pragma unroll
    for (int mi = 0; mi < 2; ++mi)
        #pragma unroll
        for (int ni = 0; ni < 2; ++ni) {
            int n = n0 + wn * 32 + ni * 16 + colb;
            #pragma unroll
            for (int r = 0; r < 4; ++r) {
                int ml = wm * 32 + mi * 16 + rquad + r;
                if (m0 + ml < cnt) {
                    int tok = perm[off + m0 + ml];
                    out[(size_t)tok * DDIM + n] = acc[mi][ni][r];
                }
            }
        }
}

extern "C" void kernel_launch(void* const* d_in, const int* in_sizes, int n_in,
                              void* d_out, int out_size, void* d_ws, size_t ws_size,
                              hipStream_t stream) {
    const float* x      = (const float*)d_in[0];
    const int*   pos    = (const int*)d_in[1];
    const float* gate_w = (const float*)d_in[3];
    const float* up_w   = (const float*)d_in[4];
    const float* down_w = (const float*)d_in[5];
    float* out = (float*)d_out;

    char* ws = (char*)d_ws;
    int* ws_i = (int*)ws;
    int* perm = (int*)(ws + 1024);
    unsigned short* xg = (unsigned short*)(ws + 32768);      // 6.3 MB bf16
    unsigned short* hg = (unsigned short*)(ws + (8u << 20)); // 16.8 MB bf16

    k_sort<<<dim3(1), dim3(1024), 0, stream>>>(pos, ws_i, perm);
    k_gather<<<dim3(T_TOK), dim3(192), 0, stream>>>(x, perm, xg);

    dim3 g1(IDIM / 64, T_TOK / 128, NEXP);
    k_gemm1<<<g1, dim3(256), 0, stream>>>(xg, gate_w, up_w, hg, ws_i);
    dim3 g2(DDIM / 64, T_TOK / 64, NEXP);   // full-K, no split
    k_gemm2<<<g2, dim3(256), 0, stream>>>(hg, down_w, out, ws_i, perm);
}

// Round 2
// 284.604 us; speedup vs baseline: 1.5011x; 1.5011x over previous
//
#include <hip/hip_runtime.h>
#include <hip/hip_bf16.h>

#define T_TOK 4096
#define DDIM  768
#define IDIM  2048
#define NEXP  8
#define LSTR  40   // gemm1 LDS row stride in bf16 (80 B): 20-bank rotation, ~2-way (free)
#define LSTR2 72   // gemm2 LDS row stride in bf16 (144 B): 4-bank rotation, ~2-way

typedef __attribute__((ext_vector_type(8))) short  bfrag;   // 8 bf16 = 4 VGPR
typedef __attribute__((ext_vector_type(4))) float  ffrag;   // 4 f32 acc

static __device__ __forceinline__ unsigned short f2bf(float f) {
    union { float f; unsigned u; } v; v.f = f;
    unsigned r = v.u + 0x7FFFu + ((v.u >> 16) & 1u);   // RNE
    return (unsigned short)(r >> 16);
}

static __device__ __forceinline__ unsigned cvt2(float x, float y) {
    return (unsigned)f2bf(x) | ((unsigned)f2bf(y) << 16);
}

static __device__ __forceinline__ uint4 cvt8(float4 a, float4 b) {
    uint4 o;
    o.x = cvt2(a.x, a.y); o.y = cvt2(a.z, a.w);
    o.z = cvt2(b.x, b.y); o.w = cvt2(b.z, b.w);
    return o;
}

// Barrier that does NOT drain vmcnt: prefetched global loads stay in flight.
// lgkmcnt(0) seals this wave's ds ops; barrier => all waves' writes visible.
#define PIPE_BAR() do { \
    asm volatile("s_waitcnt lgkmcnt(0)" ::: "memory"); \
    __builtin_amdgcn_s_barrier(); \
    __builtin_amdgcn_sched_barrier(0); \
} while (0)

// ws int layout: counts[8] @0, offsets[9] @16
__global__ void k_sort(const int* __restrict__ pos, int* __restrict__ ws_i,
                       int* __restrict__ perm) {
    __shared__ int hist[NEXP], cursor[NEXP];
    const int tid = threadIdx.x;
    if (tid < NEXP) hist[tid] = 0;
    __syncthreads();
    for (int i = tid; i < T_TOK; i += 1024)
        atomicAdd(&hist[pos[i]], 1);
    __syncthreads();
    if (tid == 0) {
        int s = 0;
        for (int e = 0; e < NEXP; ++e) {
            cursor[e] = s;
            ws_i[e] = hist[e];
            ws_i[16 + e] = s;
            s += hist[e];
        }
        ws_i[16 + NEXP] = s;
    }
    __syncthreads();
    for (int i = tid; i < T_TOK; i += 1024) {
        int p = atomicAdd(&cursor[pos[i]], 1);
        perm[p] = i;
    }
}

// GEMM1 (gather fused): x[perm] fp32 -> bf16 @ gate/up^T -> h = silu(g)*u, bf16
// BM=128, BN=64 (x2 matrices), BK=32; LDS double-buffer, single-set reg prefetch,
// one non-draining barrier per K-step.
__launch_bounds__(256, 2)
__global__ void k_gemm1(const float* __restrict__ x,
                        const int* __restrict__ perm,
                        const float* __restrict__ gate_w,
                        const float* __restrict__ up_w,
                        unsigned short* __restrict__ hg,
                        const int* __restrict__ ws_i) {
    const int e   = blockIdx.z;
    const int cnt = ws_i[e];
    const int m0  = blockIdx.y * 128;
    if (m0 >= cnt) return;
    const int off = ws_i[16 + e];
    const int n0  = blockIdx.x * 64;

    const int tid  = threadIdx.x;
    const int lane = tid & 63;
    const int wave = tid >> 6;
    const int wm   = wave & 1;
    const int wn   = wave >> 1;

    __shared__ __align__(16) unsigned short lsA[2][128 * LSTR];  // 20 KB
    __shared__ __align__(16) unsigned short lsG[2][64 * LSTR];   // 10 KB
    __shared__ __align__(16) unsigned short lsU[2][64 * LSTR];   // 10 KB

    const float* gate_e = gate_w + (size_t)e * (IDIM * DDIM);
    const float* up_e   = up_w   + (size_t)e * (IDIM * DDIM);

    // staging maps: A 128 rows x 32 cols fp32 (gathered), 16 floats/thread
    const int arow = tid >> 1, aq = tid & 1;     // row 0..127, col-half 0/1
    const int brow = tid >> 2, bq = tid & 3;     // row 0..63,  col-oct  0..3

    int trow = off + m0 + arow; if (trow > T_TOK - 1) trow = T_TOK - 1;
    const int tok = perm[trow];
    const float* ap = x + (size_t)tok * DDIM + aq * 16;
    const float* gp = gate_e + (size_t)(n0 + brow) * DDIM + bq * 8;
    const float* up = up_e   + (size_t)(n0 + brow) * DDIM + bq * 8;

    ffrag accG[4][2], accU[4][2];
    const ffrag fz = {0.f, 0.f, 0.f, 0.f};
    for (int mi = 0; mi < 4; ++mi)
        for (int ni = 0; ni < 2; ++ni) { accG[mi][ni] = fz; accU[mi][ni] = fz; }

    const int koff = (lane >> 4) * 8;
    const int rsel = lane & 15;

    // single prefetch set: 8 float4 = 32 VGPR
    float4 Pa0, Pa1, Pa2, Pa3, Pg0, Pg1, Pu0, Pu1;

#define G1_LOAD(kb) do { \
    Pa0 = *reinterpret_cast<const float4*>(ap + (kb)); \
    Pa1 = *reinterpret_cast<const float4*>(ap + (kb) + 4); \
    Pa2 = *reinterpret_cast<const float4*>(ap + (kb) + 8); \
    Pa3 = *reinterpret_cast<const float4*>(ap + (kb) + 12); \
    Pg0 = *reinterpret_cast<const float4*>(gp + (kb)); \
    Pg1 = *reinterpret_cast<const float4*>(gp + (kb) + 4); \
    Pu0 = *reinterpret_cast<const float4*>(up + (kb)); \
    Pu1 = *reinterpret_cast<const float4*>(up + (kb) + 4); } while (0)

#define G1_STORE(B) do { \
    *reinterpret_cast<uint4*>(&lsA[B][arow * LSTR + aq * 16])     = cvt8(Pa0, Pa1); \
    *reinterpret_cast<uint4*>(&lsA[B][arow * LSTR + aq * 16 + 8]) = cvt8(Pa2, Pa3); \
    *reinterpret_cast<uint4*>(&lsG[B][brow * LSTR + bq * 8]) = cvt8(Pg0, Pg1); \
    *reinterpret_cast<uint4*>(&lsU[B][brow * LSTR + bq * 8]) = cvt8(Pu0, Pu1); } while (0)

#define G1_COMPUTE(B) do { \
    bfrag a[4], bg[2], bu[2]; \
    _Pragma("unroll") \
    for (int mi = 0; mi < 4; ++mi) \
        a[mi] = *reinterpret_cast<const bfrag*>(&lsA[B][(wm * 64 + mi * 16 + rsel) * LSTR + koff]); \
    _Pragma("unroll") \
    for (int ni = 0; ni < 2; ++ni) { \
        bg[ni] = *reinterpret_cast<const bfrag*>(&lsG[B][(wn * 32 + ni * 16 + rsel) * LSTR + koff]); \
        bu[ni] = *reinterpret_cast<const bfrag*>(&lsU[B][(wn * 32 + ni * 16 + rsel) * LSTR + koff]); \
    } \
    _Pragma("unroll") \
    for (int mi = 0; mi < 4; ++mi) { \
        _Pragma("unroll") \
        for (int ni = 0; ni < 2; ++ni) { \
            accG[mi][ni] = __builtin_amdgcn_mfma_f32_16x16x32_bf16(a[mi], bg[ni], accG[mi][ni], 0, 0, 0); \
            accU[mi][ni] = __builtin_amdgcn_mfma_f32_16x16x32_bf16(a[mi], bu[ni], accU[mi][ni], 0, 0, 0); \
        } \
    } } while (0)

    // prologue: tile0 -> lds[0]; tile1 loads in flight across barrier
    G1_LOAD(0);
    G1_STORE(0);
    G1_LOAD(32);
    PIPE_BAR();

    #pragma unroll 2
    for (int kt = 0; kt < 24; ++kt) {
        const int cur = kt & 1;
        if (kt < 23) G1_STORE(cur ^ 1);        // waits vmcnt via reg dep (tile kt+1)
        if (kt < 22) G1_LOAD((kt + 2) * 32);   // issue; flies across barrier
        G1_COMPUTE(cur);
        PIPE_BAR();
    }
#undef G1_LOAD
#undef G1_STORE
#undef G1_COMPUTE

    // epilogue: h = silu(g)*u; C layout col=lane&15, row=(lane>>4)*4+r
    const int colb  = lane & 15;
    const int rquad = (lane >> 4) * 4;
    #pragma unroll
    for (int mi = 0; mi < 4; ++mi)
        #pragma unroll
        for (int ni = 0; ni < 2; ++ni) {
            int n = n0 + wn * 32 + ni * 16 + colb;
            #pragma unroll
            for (int r = 0; r < 4; ++r) {
                int ml = wm * 64 + mi * 16 + rquad + r;
                if (m0 + ml < cnt) {
                    float g = accG[mi][ni][r];
                    float u = accU[mi][ni][r];
                    float h = (g / (1.0f + __expf(-g))) * u;
                    hg[(size_t)(off + m0 + ml) * IDIM + n] = f2bf(h);
                }
            }
        }
}

// GEMM2: hg[cnt x 2048] bf16 @ down^T, full K (no split-K, no atomics),
// BM=64, BN=64, BK=64; same pipeline; direct permuted store.
__launch_bounds__(256, 4)
__global__ void k_gemm2(const unsigned short* __restrict__ hg,
                        const float* __restrict__ down_w,
                        float* __restrict__ out,
                        const int* __restrict__ ws_i,
                        const int* __restrict__ perm) {
    const int e   = blockIdx.z;
    const int cnt = ws_i[e];
    const int m0  = blockIdx.y * 64;
    if (m0 >= cnt) return;
    const int off = ws_i[16 + e];
    const int n0  = blockIdx.x * 64;

    const int tid  = threadIdx.x;
    const int lane = tid & 63;
    const int wave = tid >> 6;
    const int wm   = wave & 1;
    const int wn   = wave >> 1;

    __shared__ __align__(16) unsigned short lsA[2][64 * LSTR2];  // 18 KB
    __shared__ __align__(16) unsigned short lsB[2][64 * LSTR2];  // 18 KB

    const float* down_e = down_w + (size_t)e * (DDIM * IDIM);

    // staging maps: 64 rows x 64 cols per tile, 16 elems/thread
    const int arow = tid >> 2, aq = tid & 3;

    int g0 = off + m0 + arow; if (g0 > T_TOK - 1) g0 = T_TOK - 1;
    const unsigned short* ap = hg + (size_t)g0 * IDIM + aq * 16;
    const float* bp = down_e + (size_t)(n0 + arow) * IDIM + aq * 16;

    ffrag acc[2][2];
    const ffrag fz = {0.f, 0.f, 0.f, 0.f};
    for (int mi = 0; mi < 2; ++mi)
        for (int ni = 0; ni < 2; ++ni) acc[mi][ni] = fz;

    const int koff = (lane >> 4) * 8;
    const int rsel = lane & 15;

    uint4  Pa0, Pa1;              // 16 bf16
    float4 Pb0, Pb1, Pb2, Pb3;    // 16 fp32

#define G2_LOAD(kb) do { \
    Pa0 = *reinterpret_cast<const uint4*>(ap + (kb)); \
    Pa1 = *reinterpret_cast<const uint4*>(ap + (kb) + 8); \
    Pb0 = *reinterpret_cast<const float4*>(bp + (kb)); \
    Pb1 = *reinterpret_cast<const float4*>(bp + (kb) + 4); \
    Pb2 = *reinterpret_cast<const float4*>(bp + (kb) + 8); \
    Pb3 = *reinterpret_cast<const float4*>(bp + (kb) + 12); } while (0)

#define G2_STORE(B) do { \
    *reinterpret_cast<uint4*>(&lsA[B][arow * LSTR2 + aq * 16])     = Pa0; \
    *reinterpret_cast<uint4*>(&lsA[B][arow * LSTR2 + aq * 16 + 8]) = Pa1; \
    *reinterpret_cast<uint4*>(&lsB[B][arow * LSTR2 + aq * 16])     = cvt8(Pb0, Pb1); \
    *reinterpret_cast<uint4*>(&lsB[B][arow * LSTR2 + aq * 16 + 8]) = cvt8(Pb2, Pb3); } while (0)

#define G2_COMPUTE(B) do { \
    _Pragma("unroll") \
    for (int h = 0; h < 2; ++h) { \
        const int ko = h * 32 + koff; \
        bfrag a[2], b[2]; \
        _Pragma("unroll") \
        for (int mi = 0; mi < 2; ++mi) \
            a[mi] = *reinterpret_cast<const bfrag*>(&lsA[B][(wm * 32 + mi * 16 + rsel) * LSTR2 + ko]); \
        _Pragma("unroll") \
        for (int ni = 0; ni < 2; ++ni) \
            b[ni] = *reinterpret_cast<const bfrag*>(&lsB[B][(wn * 32 + ni * 16 + rsel) * LSTR2 + ko]); \
        _Pragma("unroll") \
        for (int mi = 0; mi < 2; ++mi) { \
            _Pragma("unroll") \
            for (int ni = 0; ni < 2; ++ni) \
                acc[mi][ni] = __builtin_amdgcn_mfma_f32_16x16x32_bf16(a[mi], b[ni], acc[mi][ni], 0, 0, 0); \
        } \
    } } while (0)

    G2_LOAD(0);
    G2_STORE(0);
    G2_LOAD(64);
    PIPE_BAR();

    #pragma unroll 2
    for (int kt = 0; kt < 32; ++kt) {
        const int cur = kt & 1;
        if (kt < 31) G2_STORE(cur ^ 1);
        if (kt < 30) G2_LOAD((kt + 2) * 64);
        G2_COMPUTE(cur);
        PIPE_BAR();
    }
#undef G2_LOAD
#undef G2_STORE
#undef G2_COMPUTE

    // epilogue: direct permuted store (each (tok, n) written exactly once)
    const int colb  = lane & 15;
    const int rquad = (lane >> 4) * 4;
    #pragma unroll
    for (int mi = 0; mi < 2; ++mi)
        #pragma unroll
        for (int ni = 0; ni < 2; ++ni) {
            int n = n0 + wn * 32 + ni * 16 + colb;
            #pragma unroll
            for (int r = 0; r < 4; ++r) {
                int ml = wm * 32 + mi * 16 + rquad + r;
                if (m0 + ml < cnt) {
                    int tok = perm[off + m0 + ml];
                    out[(size_t)tok * DDIM + n] = acc[mi][ni][r];
                }
            }
        }
}

extern "C" void kernel_launch(void* const* d_in, const int* in_sizes, int n_in,
                              void* d_out, int out_size, void* d_ws, size_t ws_size,
                              hipStream_t stream) {
    const float* x      = (const float*)d_in[0];
    const int*   pos    = (const int*)d_in[1];
    const float* gate_w = (const float*)d_in[3];
    const float* up_w   = (const float*)d_in[4];
    const float* down_w = (const float*)d_in[5];
    float* out = (float*)d_out;

    char* ws = (char*)d_ws;
    int* ws_i = (int*)ws;
    int* perm = (int*)(ws + 1024);
    unsigned short* hg = (unsigned short*)(ws + 32768);   // 16.8 MB bf16

    k_sort<<<dim3(1), dim3(1024), 0, stream>>>(pos, ws_i, perm);

    dim3 g1(IDIM / 64, T_TOK / 128, NEXP);
    k_gemm1<<<g1, dim3(256), 0, stream>>>(x, perm, gate_w, up_w, hg, ws_i);
    dim3 g2(DDIM / 64, T_TOK / 64, NEXP);
    k_gemm2<<<g2, dim3(256), 0, stream>>>(hg, down_w, out, ws_i, perm);
}